// Round 6
// baseline (5945.327 us; speedup 1.0000x reference)
//
#include <hip/hip_runtime.h>
#include <hip/hip_bf16.h>
#include <math.h>
#include <stdint.h>

// Problem constants
#define T_TOK 4096
#define H_DIM 2880
#define E_NUM 16
#define ALPHA 1.702f
#define EPS_RMS 1e-5f

// GEMM tiling: BM=192 (4 waves x 3 m-frags), BN=192 effective, BK=32.
// A: 3-buffer LDS, depth-2 prefetch via global_load_lds (register-free).
// B: 3-buffer LDS, single 24-VGPR bv set; load at step kt-1, pack at step kt
//    (full-step latency cover). NO vmcnt(0) in steady state; tail drains once.
#define PADM 192
#define BK 32
#define NK (H_DIM / BK)       // 90 (divisible by 3)
#define MAX_RT 104
#define NCT1 30               // gemm1 col tiles of 96 (+96 lin)
#define NCT2 15               // gemm2 col tiles of 192
#define G1 (MAX_RT * NCT1)    // 3120 (div 8)
#define G2 (MAX_RT * NCT2)    // 1560 (div 8)
#define ABUF 12288            // A buffer: 192 rows x 64 B  (x3)
#define BBUF 12288            // B buffer: 192 rows x 64 B  (x3)
#define BOFF 36864            // B region base; total LDS 72 KB

typedef __attribute__((ext_vector_type(8))) short short8;
typedef __attribute__((ext_vector_type(4))) float f32x4;

__device__ __forceinline__ unsigned short f2bf(float f) {
  unsigned u = __float_as_uint(f);
  return (unsigned short)((u + 0x7fffu + ((u >> 16) & 1u)) >> 16);
}
// packed f32x2 -> bf16x2 in one VALU inst (RNE), lo=a hi=b
__device__ __forceinline__ unsigned cpk(float a, float b) {
  unsigned r;
  asm("v_cvt_pk_bf16_f32 %0, %1, %2" : "=v"(r) : "v"(a), "v"(b));
  return r;
}
__device__ __forceinline__ void gl_lds16(const void* g, unsigned char* lds_dst) {
  __builtin_amdgcn_global_load_lds(
      (const __attribute__((address_space(1))) void*)g,
      (__attribute__((address_space(3))) void*)lds_dst, 16, 0, 0);
}
// end-of-step barrier: LDS ops done; vmem prefetches stay in flight
#define ENDSTEP() do {                                           \
    asm volatile("s_waitcnt lgkmcnt(0)" ::: "memory");           \
    __builtin_amdgcn_s_barrier();                                \
    __builtin_amdgcn_sched_barrier(0);                           \
  } while (0)

// ---------------- K1: rmsnorm + residual copy + fp32 gate + top4 ----------------
__global__ __launch_bounds__(256) void k_norm_gate(
    const float* __restrict__ x, const float* __restrict__ norm_w,
    const float* __restrict__ gate_w, const float* __restrict__ gate_b,
    float* __restrict__ out, unsigned short* __restrict__ t_out,
    int* __restrict__ topk_id, float* __restrict__ topk_w,
    int* __restrict__ counts)
{
  int t = blockIdx.x, tid = threadIdx.x;
  const float4* xr = (const float4*)(x + (size_t)t * H_DIM);
  float4* outr = (float4*)(out + (size_t)t * H_DIM);
  float4 xa[3];
  float ss = 0.f;
  int j = 0;
  for (int i = tid; i < 720; i += 256, j++) {
    float4 v = xr[i]; xa[j] = v; outr[i] = v;    // residual: out = x
    ss += v.x * v.x + v.y * v.y + v.z * v.z + v.w * v.w;
  }
#pragma unroll
  for (int o = 1; o < 64; o <<= 1) ss += __shfl_xor(ss, o, 64);
  __shared__ float red[4];
  if ((tid & 63) == 0) red[tid >> 6] = ss;
  __syncthreads();
  float rs = rsqrtf((red[0] + red[1] + red[2] + red[3]) * (1.f / H_DIM) + EPS_RMS);

  float part[16];
#pragma unroll
  for (int q = 0; q < 16; q++) part[q] = 0.f;
  j = 0;
  for (int i = tid; i < 720; i += 256, j++) {
    float4 v = xa[j];
    float4 w = ((const float4*)norm_w)[i];
    float t0 = v.x * rs * w.x, t1 = v.y * rs * w.y;
    float t2 = v.z * rs * w.z, t3 = v.w * rs * w.w;
    ushort4 b; b.x = f2bf(t0); b.y = f2bf(t1); b.z = f2bf(t2); b.w = f2bf(t3);
    ((ushort4*)(t_out + (size_t)t * H_DIM))[i] = b;
#pragma unroll
    for (int q = 0; q < 16; q++) {    // fp32 logits (selection accuracy)
      float4 g = ((const float4*)(gate_w + (size_t)q * H_DIM))[i];
      part[q] += t0 * g.x + t1 * g.y + t2 * g.z + t3 * g.w;
    }
  }
  __shared__ float lg[4][16];
#pragma unroll
  for (int q = 0; q < 16; q++) {
    float p = part[q];
#pragma unroll
    for (int o = 1; o < 64; o <<= 1) p += __shfl_xor(p, o, 64);
    if ((tid & 63) == 0) lg[tid >> 6][q] = p;
  }
  __syncthreads();
  if (tid == 0) {
    float logit[16];
    for (int q = 0; q < 16; q++)
      logit[q] = lg[0][q] + lg[1][q] + lg[2][q] + lg[3][q] + gate_b[q];
    unsigned used = 0; int idx[4]; float val[4];
    for (int k = 0; k < 4; k++) {           // ties -> lowest index
      float best = -3.4e38f; int bi = 0;
      for (int q = 0; q < 16; q++)
        if (!((used >> q) & 1u) && logit[q] > best) { best = logit[q]; bi = q; }
      used |= 1u << bi; idx[k] = bi; val[k] = best;
    }
    float s0 = 0.f, w4[4];
    for (int k = 0; k < 4; k++) { w4[k] = expf(val[k] - val[0]); s0 += w4[k]; }
    for (int k = 0; k < 4; k++) {
      topk_id[t * 4 + k] = idx[k];
      topk_w[t * 4 + k] = w4[k] / s0;
      atomicAdd(&counts[idx[k]], 1);
    }
  }
}

// ---------------- K2a: padded prefix offsets ----------------
__global__ void k_offsets(const int* __restrict__ counts, int* __restrict__ d_off) {
  if (threadIdx.x == 0) {
    int acc = 0;
    for (int q = 0; q < 16; q++) {
      d_off[q] = acc;
      acc += ((counts[q] + PADM - 1) / PADM) * PADM;
    }
    d_off[16] = acc;
  }
}

// ---------------- K2b: deterministic token-ordered routing lists ----------------
__global__ __launch_bounds__(256) void k_fill(
    const int* __restrict__ topk_id, const float* __restrict__ topk_w,
    const int* __restrict__ counts, const int* __restrict__ d_off,
    int* __restrict__ perm_tok, float* __restrict__ perm_w)
{
  int e = blockIdx.x;
  int base = d_off[e], pe = d_off[e + 1] - base, cnt = counts[e];
  int tid = threadIdx.x, lane = tid & 63, wv = tid >> 6;
  __shared__ int wsum[4];
  int pos = 0;
  for (int c0 = 0; c0 < T_TOK; c0 += 256) {
    int tok = c0 + tid;
    int4 ids = ((const int4*)topk_id)[tok];
    int flag = 0, slot = 0;
    if (ids.x == e) { flag = 1; slot = 0; }
    else if (ids.y == e) { flag = 1; slot = 1; }
    else if (ids.z == e) { flag = 1; slot = 2; }
    else if (ids.w == e) { flag = 1; slot = 3; }
    unsigned long long b = __ballot(flag);
    int wprefix = __popcll(b & ((1ULL << lane) - 1ULL));
    if (lane == 0) wsum[wv] = __popcll(b);
    __syncthreads();
    int woff = 0;
    for (int i = 0; i < wv; i++) woff += wsum[i];
    int tot = wsum[0] + wsum[1] + wsum[2] + wsum[3];
    if (flag) {
      int p = base + pos + woff + wprefix;
      perm_tok[p] = tok;
      perm_w[p] = topk_w[tok * 4 + slot];
    }
    pos += tot;
    __syncthreads();
  }
  for (int i = cnt + tid; i < pe; i += 256) {   // padding rows: token 0, weight 0
    perm_tok[base + i] = 0;
    perm_w[base + i] = 0.f;
  }
}

// ---- shared GEMM macros ----
#define STAGE_A(abuf, ktn) do {                                               \
  _Pragma("unroll")                                                           \
  for (int i = 0; i < 3; i++)                                                 \
    gl_lds16(aptr[i] + (size_t)(ktn) * BK, lds + (abuf) * ABUF + adst[i]);    \
} while (0)

#define LOAD_B(ktn) do {                                                      \
  _Pragma("unroll")                                                           \
  for (int j = 0; j < 3; j++) {                                               \
    bv[j][0] = bptr[j][(ktn) * 8];                                            \
    bv[j][1] = bptr[j][(ktn) * 8 + 1];                                        \
  }                                                                           \
} while (0)

#define PACK_B(bbuf) do {                                                     \
  _Pragma("unroll")                                                           \
  for (int j = 0; j < 3; j++) {                                               \
    uint4 p;                                                                  \
    p.x = cpk(bv[j][0].x, bv[j][0].y); p.y = cpk(bv[j][0].z, bv[j][0].w);     \
    p.z = cpk(bv[j][1].x, bv[j][1].y); p.w = cpk(bv[j][1].z, bv[j][1].w);     \
    *(uint4*)(lds + BOFF + (bbuf) * BBUF + bdst[j]) = p;                      \
  }                                                                           \
} while (0)

#define COMPUTE(cb) do {                                                      \
  const unsigned char* Abase = lds + (cb) * ABUF + abase_off;                 \
  const unsigned char* Bbase = lds + BOFF + (cb) * BBUF + bbase_off;          \
  short8 a0 = *(const short8*)(Abase);                                        \
  short8 a1 = *(const short8*)(Abase + 1024);                                 \
  short8 a2 = *(const short8*)(Abase + 2048);                                 \
  __builtin_amdgcn_s_setprio(1);                                              \
  _Pragma("unroll")                                                           \
  for (int n = 0; n < 12; n++) {                                              \
    short8 b = *(const short8*)(Bbase + n * 1024);                            \
    acc[0][n] = __builtin_amdgcn_mfma_f32_16x16x32_bf16(a0, b, acc[0][n], 0, 0, 0); \
    acc[1][n] = __builtin_amdgcn_mfma_f32_16x16x32_bf16(a1, b, acc[1][n], 0, 0, 0); \
    acc[2][n] = __builtin_amdgcn_mfma_f32_16x16x32_bf16(a2, b, acc[2][n], 0, 0, 0); \
  }                                                                           \
  __builtin_amdgcn_s_setprio(0);                                              \
} while (0)

// Step kt (PB == (kt+2)%3 == compute/stage/pack rotation):
//   STAGE_A(PB, kt+2)          A depth-2, register-free, stays in flight
//   COMPUTE(kt%3)              36 MFMA
//   [sched_barrier] PACK_B(PB) bv holds B(kt+2), loaded at END of step kt-1
//                              -> full-step latency cover; vmcnt wait lands
//                              after the MFMA cluster (pinned)
//   LOAD_B(kt+3)               refill bv for next step's pack
//   lgkmcnt(0); s_barrier      (vmem stays in flight)
// A-landing guarantee: pack at step kt-1 waits B(kt+1), issued after
// STAGE_A(kt) -> in-order vmcnt implies A(kt) landed. Tail (no packs left)
// drains vmcnt(0) once - covers A(NK-1).
#define GEMM_STEP(kt, CB, PB) do {                                            \
    if ((kt) + 2 < NK) STAGE_A(PB, (kt) + 2);                                 \
    COMPUTE(CB);                                                              \
    __builtin_amdgcn_sched_barrier(0);                                        \
    if ((kt) + 2 < NK) PACK_B(PB);                                            \
    else asm volatile("s_waitcnt vmcnt(0)" ::: "memory");                     \
    if ((kt) + 3 < NK) LOAD_B((kt) + 3);                                      \
    ENDSTEP();                                                                \
  } while (0)

#define GEMM_PIPE() do {                                                      \
  STAGE_A(0, 0); STAGE_A(1, 1);                                               \
  LOAD_B(0); PACK_B(0);                                                       \
  LOAD_B(1); PACK_B(1);   /* waits B(1): issued after A(0),A(1) -> landed */  \
  LOAD_B(2);              /* lives in bv until step 0's pack */               \
  ENDSTEP();                                                                  \
  _Pragma("unroll 1")                                                         \
  for (int u = 0; u < NK / 3; u++) {                                          \
    int kt = 3 * u;                                                           \
    GEMM_STEP(kt,     0, 2);                                                  \
    GEMM_STEP(kt + 1, 1, 0);                                                  \
    GEMM_STEP(kt + 2, 2, 1);                                                  \
  }                                                                           \
} while (0)

// ================= K3: grouped gemm1 + bias + SwiGLU -> act =================
__global__ __launch_bounds__(256, 2) void k_gemm1(
    const unsigned short* __restrict__ t_bf16,
    const float* __restrict__ w1, const float* __restrict__ b1,
    const int* __restrict__ perm_tok, const int* __restrict__ d_off,
    unsigned short* __restrict__ act)
{
  __shared__ __align__(16) unsigned char lds[3 * ABUF + 3 * BBUF];  // 72 KB
  const int total = d_off[16];
  int bid = blockIdx.x;
  int wg = (bid & 7) * (G1 / 8) + (bid >> 3);   // XCD-chunked, rt fastest
  int ct = wg / MAX_RT, rt = wg % MAX_RT;
  int rowbase = rt * PADM;
  if (rowbase >= total) return;
  int e = 0;
#pragma unroll
  for (int q = 0; q < E_NUM; q++) if (d_off[q + 1] <= rowbase) e = q + 1;

  int tid = threadIdx.x, lane = tid & 63, wv = tid >> 6;
  int lr = lane & 15, ch = lane >> 4;
  unsigned swz16 = (unsigned)((ch ^ ((lr >> 1) & 3)) << 4);
  unsigned abase_off = (unsigned)(wv * 3072 + lr * 64) + swz16;
  unsigned bbase_off = (unsigned)(lr * 64) + swz16;

  // A staging: gload_lds linear dst, pre-swizzled source chunk
  const unsigned short* aptr[3]; unsigned adst[3];
#pragma unroll
  for (int i = 0; i < 3; i++) {
    int cl = tid + 256 * i;                 // 0..767
    int r = cl >> 2, c = cl & 3;
    int tok = perm_tok[rowbase + r];
    aptr[i] = t_bf16 + (size_t)tok * H_DIM + ((c ^ ((r >> 1) & 3)) * 8);
    adst[i] = (unsigned)cl * 16;
  }
  // B staging: linear fp32 source, dst-swizzled ds_write
  const float4* bptr[3]; unsigned bdst[3];
#pragma unroll
  for (int j = 0; j < 3; j++) {
    int idx = tid + 256 * j;                // 0..767
    int rr = idx >> 2, c = idx & 3;
    size_t grow = (size_t)e * (2 * H_DIM) +
                  (rr < 96 ? (size_t)(ct * 96 + rr) : (size_t)(H_DIM + ct * 96 + (rr - 96)));
    bptr[j] = (const float4*)(w1 + grow * H_DIM) + c * 2;
    bdst[j] = (unsigned)(rr * 64 + ((c ^ ((rr >> 1) & 3)) << 4));
  }

  f32x4 zero = {0.f, 0.f, 0.f, 0.f};
  f32x4 acc[3][12];
#pragma unroll
  for (int m = 0; m < 3; m++)
#pragma unroll
    for (int n = 0; n < 12; n++) acc[m][n] = zero;
  float4 bv[3][2];

  GEMM_PIPE();

  // epilogue: bias + SwiGLU, store act bf16
  int rq = lane >> 4;
#pragma unroll
  for (int m = 0; m < 3; m++) {
    int row0 = rowbase + wv * 48 + m * 16 + rq * 4;
#pragma unroll
    for (int n = 0; n < 6; n++) {
      int col = ct * 96 + n * 16 + lr;
      float bg = b1[(size_t)e * (2 * H_DIM) + col];
      float bl = b1[(size_t)e * (2 * H_DIM) + H_DIM + col];
#pragma unroll
      for (int j = 0; j < 4; j++) {
        float g = acc[m][n][j] + bg;
        float l = acc[m][n + 6][j] + bl;
        float s = 1.f / (1.f + __expf(-ALPHA * g));
        act[(size_t)(row0 + j) * H_DIM + col] = f2bf(g * s * (l + 1.f));
      }
    }
  }
}

// ================= K4: grouped gemm2 + bias, weighted atomic scatter =================
__global__ __launch_bounds__(256, 2) void k_gemm2(
    const unsigned short* __restrict__ act,
    const float* __restrict__ w2, const float* __restrict__ b2,
    const int* __restrict__ perm_tok, const float* __restrict__ perm_w,
    const int* __restrict__ d_off,
    float* __restrict__ out)
{
  __shared__ __align__(16) unsigned char lds[3 * ABUF + 3 * BBUF];  // 72 KB
  __shared__ int stok[PADM]; __shared__ float swt[PADM];
  const int total = d_off[16];
  int bid = blockIdx.x;
  int wg = (bid & 7) * (G2 / 8) + (bid >> 3);
  int ct = wg / MAX_RT, rt = wg % MAX_RT;
  int rowbase = rt * PADM;
  if (rowbase >= total) return;
  int e = 0;
#pragma unroll
  for (int q = 0; q < E_NUM; q++) if (d_off[q + 1] <= rowbase) e = q + 1;

  int tid = threadIdx.x, lane = tid & 63, wv = tid >> 6;
  int lr = lane & 15, ch = lane >> 4;
  unsigned swz16 = (unsigned)((ch ^ ((lr >> 1) & 3)) << 4);
  unsigned abase_off = (unsigned)(wv * 3072 + lr * 64) + swz16;
  unsigned bbase_off = (unsigned)(lr * 64) + swz16;

  if (tid < PADM) { stok[tid] = perm_tok[rowbase + tid]; swt[tid] = perm_w[rowbase + tid]; }

  const unsigned short* aptr[3]; unsigned adst[3];
#pragma unroll
  for (int i = 0; i < 3; i++) {
    int cl = tid + 256 * i;
    int r = cl >> 2, c = cl & 3;
    aptr[i] = act + (size_t)(rowbase + r) * H_DIM + ((c ^ ((r >> 1) & 3)) * 8);
    adst[i] = (unsigned)cl * 16;
  }
  const float4* bptr[3]; unsigned bdst[3];
#pragma unroll
  for (int j = 0; j < 3; j++) {
    int idx = tid + 256 * j;
    int rr = idx >> 2, c = idx & 3;
    size_t grow = (size_t)e * H_DIM + (size_t)(ct * 192 + rr);
    bptr[j] = (const float4*)(w2 + grow * H_DIM) + c * 2;
    bdst[j] = (unsigned)(rr * 64 + ((c ^ ((rr >> 1) & 3)) << 4));
  }

  f32x4 zero = {0.f, 0.f, 0.f, 0.f};
  f32x4 acc[3][12];
#pragma unroll
  for (int m = 0; m < 3; m++)
#pragma unroll
    for (int n = 0; n < 12; n++) acc[m][n] = zero;
  float4 bv[3][2];

  GEMM_PIPE();

  // epilogue: bias + weighted atomic scatter
  int rq = lane >> 4;
#pragma unroll
  for (int m = 0; m < 3; m++) {
    int rl0 = wv * 48 + m * 16 + rq * 4;
#pragma unroll
    for (int n = 0; n < 12; n++) {
      int col = ct * 192 + n * 16 + lr;
      float b2v = b2[(size_t)e * H_DIM + col];
#pragma unroll
      for (int j = 0; j < 4; j++) {
        int rl = rl0 + j;
        float w = swt[rl];
        if (w != 0.f)
          atomicAdd(out + (size_t)stok[rl] * H_DIM + col, (acc[m][n][j] + b2v) * w);
      }
    }
  }
}

// ---------------- launch ----------------
extern "C" void kernel_launch(void* const* d_in, const int* in_sizes, int n_in,
                              void* d_out, int out_size, void* d_ws, size_t ws_size,
                              hipStream_t stream)
{
  const float* x      = (const float*)d_in[0];
  const float* norm_w = (const float*)d_in[1];
  const float* gate_w = (const float*)d_in[2];
  const float* gate_b = (const float*)d_in[3];
  const float* w1     = (const float*)d_in[4];
  const float* b1     = (const float*)d_in[5];
  const float* w2     = (const float*)d_in[6];
  const float* b2     = (const float*)d_in[7];
  float* out = (float*)d_out;
  char* ws = (char*)d_ws;

  // ws layout (~138.9 MB)
  unsigned short* t_bf16  = (unsigned short*)(ws);                    // 23,592,960
  unsigned short* act     = (unsigned short*)(ws + 23592960);         // 115,015,680
  int*            topk_id = (int*)(ws + 138608640);                   // 65,536
  float*          topk_w  = (float*)(ws + 138674176);                 // 65,536
  int*            perm_tk = (int*)(ws + 138739712);                   // 79,872
  float*          perm_w  = (float*)(ws + 138819584);                 // 79,872
  int*            counts  = (int*)(ws + 138899456);                   // 64
  int*            d_off   = (int*)(ws + 138899520);                   // 68

  hipMemsetAsync(counts, 0, 64, stream);
  hipLaunchKernelGGL(k_norm_gate, dim3(T_TOK), dim3(256), 0, stream,
                     x, norm_w, gate_w, gate_b, out, t_bf16, topk_id, topk_w, counts);
  hipLaunchKernelGGL(k_offsets, dim3(1), dim3(64), 0, stream, counts, d_off);
  hipLaunchKernelGGL(k_fill, dim3(16), dim3(256), 0, stream,
                     topk_id, topk_w, counts, d_off, perm_tk, perm_w);
  hipLaunchKernelGGL(k_gemm1, dim3(G1), dim3(256), 0, stream,
                     t_bf16, w1, b1, perm_tk, d_off, act);
  hipLaunchKernelGGL(k_gemm2, dim3(G2), dim3(256), 0, stream,
                     act, w2, b2, perm_tk, perm_w, d_off, out);
}

// Round 7
// 2858.430 us; speedup vs baseline: 2.0799x; 2.0799x over previous
//
#include <hip/hip_runtime.h>
#include <hip/hip_bf16.h>
#include <math.h>
#include <stdint.h>

// Problem constants
#define T_TOK 4096
#define H_DIM 2880
#define E_NUM 16
#define ALPHA 1.702f
#define EPS_RMS 1e-5f

// GEMM tiling: block 192x192, BK=32. Fallback (R5): 4 waves 1x4 (64x192/wave),
// A gload_lds 3-buf depth-2, B reg-staged 3-buf. BF16W path: 4 waves 2x2
// (96x96/wave), A AND B gload_lds 3-buf depth-2, counted vmcnt(6), 1 barrier/step.
#define PADM 192
#define BK 32
#define NK (H_DIM / BK)       // 90 (divisible by 3)
#define MAX_RT 104
#define NCT1 30               // gemm1 col tiles of 96 (+96 lin)
#define NCT2 15               // gemm2 col tiles of 192
#define G1 (MAX_RT * NCT1)    // 3120 (div 8)
#define G2 (MAX_RT * NCT2)    // 1560 (div 8)
#define ABUF 12288            // A buffer: 192 rows x 64 B  (x3)
#define BBUF 12288            // B buffer: 192 rows x 64 B  (x3)
#define BOFF 36864            // B region base; total LDS 72 KB

typedef __attribute__((ext_vector_type(8))) short short8;
typedef __attribute__((ext_vector_type(4))) float f32x4;

__device__ __forceinline__ unsigned short f2bf(float f) {
  unsigned u = __float_as_uint(f);
  return (unsigned short)((u + 0x7fffu + ((u >> 16) & 1u)) >> 16);
}
// packed f32x2 -> bf16x2 in one VALU inst (RNE), lo=a hi=b
__device__ __forceinline__ unsigned cpk(float a, float b) {
  unsigned r;
  asm("v_cvt_pk_bf16_f32 %0, %1, %2" : "=v"(r) : "v"(a), "v"(b));
  return r;
}
__device__ __forceinline__ void gl_lds16(const void* g, unsigned char* lds_dst) {
  __builtin_amdgcn_global_load_lds(
      (const __attribute__((address_space(1))) void*)g,
      (__attribute__((address_space(3))) void*)lds_dst, 16, 0, 0);
}
#define ENDSTEP() do {                                           \
    asm volatile("s_waitcnt lgkmcnt(0)" ::: "memory");           \
    __builtin_amdgcn_s_barrier();                                \
    __builtin_amdgcn_sched_barrier(0);                           \
  } while (0)

// ---------------- K1: rmsnorm + residual copy + fp32 gate + top4 ----------------
__global__ __launch_bounds__(256) void k_norm_gate(
    const float* __restrict__ x, const float* __restrict__ norm_w,
    const float* __restrict__ gate_w, const float* __restrict__ gate_b,
    float* __restrict__ out, unsigned short* __restrict__ t_out,
    int* __restrict__ topk_id, float* __restrict__ topk_w,
    int* __restrict__ counts)
{
  int t = blockIdx.x, tid = threadIdx.x;
  const float4* xr = (const float4*)(x + (size_t)t * H_DIM);
  float4* outr = (float4*)(out + (size_t)t * H_DIM);
  float4 xa[3];
  float ss = 0.f;
  int j = 0;
  for (int i = tid; i < 720; i += 256, j++) {
    float4 v = xr[i]; xa[j] = v; outr[i] = v;    // residual: out = x
    ss += v.x * v.x + v.y * v.y + v.z * v.z + v.w * v.w;
  }
#pragma unroll
  for (int o = 1; o < 64; o <<= 1) ss += __shfl_xor(ss, o, 64);
  __shared__ float red[4];
  if ((tid & 63) == 0) red[tid >> 6] = ss;
  __syncthreads();
  float rs = rsqrtf((red[0] + red[1] + red[2] + red[3]) * (1.f / H_DIM) + EPS_RMS);

  float part[16];
#pragma unroll
  for (int q = 0; q < 16; q++) part[q] = 0.f;
  j = 0;
  for (int i = tid; i < 720; i += 256, j++) {
    float4 v = xa[j];
    float4 w = ((const float4*)norm_w)[i];
    float t0 = v.x * rs * w.x, t1 = v.y * rs * w.y;
    float t2 = v.z * rs * w.z, t3 = v.w * rs * w.w;
    ushort4 b; b.x = f2bf(t0); b.y = f2bf(t1); b.z = f2bf(t2); b.w = f2bf(t3);
    ((ushort4*)(t_out + (size_t)t * H_DIM))[i] = b;
#pragma unroll
    for (int q = 0; q < 16; q++) {    // fp32 logits (selection accuracy)
      float4 g = ((const float4*)(gate_w + (size_t)q * H_DIM))[i];
      part[q] += t0 * g.x + t1 * g.y + t2 * g.z + t3 * g.w;
    }
  }
  __shared__ float lg[4][16];
#pragma unroll
  for (int q = 0; q < 16; q++) {
    float p = part[q];
#pragma unroll
    for (int o = 1; o < 64; o <<= 1) p += __shfl_xor(p, o, 64);
    if ((tid & 63) == 0) lg[tid >> 6][q] = p;
  }
  __syncthreads();
  if (tid == 0) {
    float logit[16];
    for (int q = 0; q < 16; q++)
      logit[q] = lg[0][q] + lg[1][q] + lg[2][q] + lg[3][q] + gate_b[q];
    unsigned used = 0; int idx[4]; float val[4];
    for (int k = 0; k < 4; k++) {           // ties -> lowest index
      float best = -3.4e38f; int bi = 0;
      for (int q = 0; q < 16; q++)
        if (!((used >> q) & 1u) && logit[q] > best) { best = logit[q]; bi = q; }
      used |= 1u << bi; idx[k] = bi; val[k] = best;
    }
    float s0 = 0.f, w4[4];
    for (int k = 0; k < 4; k++) { w4[k] = expf(val[k] - val[0]); s0 += w4[k]; }
    for (int k = 0; k < 4; k++) {
      topk_id[t * 4 + k] = idx[k];
      topk_w[t * 4 + k] = w4[k] / s0;
      atomicAdd(&counts[idx[k]], 1);
    }
  }
}

// ---------------- K2a: padded prefix offsets ----------------
__global__ void k_offsets(const int* __restrict__ counts, int* __restrict__ d_off) {
  if (threadIdx.x == 0) {
    int acc = 0;
    for (int q = 0; q < 16; q++) {
      d_off[q] = acc;
      acc += ((counts[q] + PADM - 1) / PADM) * PADM;
    }
    d_off[16] = acc;
  }
}

// ---------------- K2b: deterministic token-ordered routing lists ----------------
__global__ __launch_bounds__(256) void k_fill(
    const int* __restrict__ topk_id, const float* __restrict__ topk_w,
    const int* __restrict__ counts, const int* __restrict__ d_off,
    int* __restrict__ perm_tok, float* __restrict__ perm_w)
{
  int e = blockIdx.x;
  int base = d_off[e], pe = d_off[e + 1] - base, cnt = counts[e];
  int tid = threadIdx.x, lane = tid & 63, wv = tid >> 6;
  __shared__ int wsum[4];
  int pos = 0;
  for (int c0 = 0; c0 < T_TOK; c0 += 256) {
    int tok = c0 + tid;
    int4 ids = ((const int4*)topk_id)[tok];
    int flag = 0, slot = 0;
    if (ids.x == e) { flag = 1; slot = 0; }
    else if (ids.y == e) { flag = 1; slot = 1; }
    else if (ids.z == e) { flag = 1; slot = 2; }
    else if (ids.w == e) { flag = 1; slot = 3; }
    unsigned long long b = __ballot(flag);
    int wprefix = __popcll(b & ((1ULL << lane) - 1ULL));
    if (lane == 0) wsum[wv] = __popcll(b);
    __syncthreads();
    int woff = 0;
    for (int i = 0; i < wv; i++) woff += wsum[i];
    int tot = wsum[0] + wsum[1] + wsum[2] + wsum[3];
    if (flag) {
      int p = base + pos + woff + wprefix;
      perm_tok[p] = tok;
      perm_w[p] = topk_w[tok * 4 + slot];
    }
    pos += tot;
    __syncthreads();
  }
  for (int i = cnt + tid; i < pe; i += 256) {   // padding rows: token 0, weight 0
    perm_tok[base + i] = 0;
    perm_w[base + i] = 0.f;
  }
}

// ---------------- weight fp32 -> bf16 conversion ----------------
__global__ __launch_bounds__(256) void k_cvt(
    const float* __restrict__ src, unsigned short* __restrict__ dst, int n8)
{
  int i = blockIdx.x * 256 + threadIdx.x;
  int stride = gridDim.x * 256;
  for (; i < n8; i += stride) {
    float4 a = ((const float4*)src)[2 * i];
    float4 b = ((const float4*)src)[2 * i + 1];
    uint4 o;
    o.x = cpk(a.x, a.y); o.y = cpk(a.z, a.w);
    o.z = cpk(b.x, b.y); o.w = cpk(b.z, b.w);
    ((uint4*)dst)[i] = o;
  }
}

// ================== Fallback (R5, proven) GEMM macros ==================
#define STAGE_A(abuf, ktn) do {                                               \
  _Pragma("unroll")                                                           \
  for (int i = 0; i < 3; i++)                                                 \
    gl_lds16(aptr[i] + (size_t)(ktn) * BK, lds + (abuf) * ABUF + adst[i]);    \
} while (0)

#define LOAD_B(ktn) do {                                                      \
  _Pragma("unroll")                                                           \
  for (int j = 0; j < 3; j++) {                                               \
    bv[j][0] = bptr[j][(ktn) * 8];                                            \
    bv[j][1] = bptr[j][(ktn) * 8 + 1];                                        \
  }                                                                           \
} while (0)

#define PACK_B(bbuf) do {                                                     \
  _Pragma("unroll")                                                           \
  for (int j = 0; j < 3; j++) {                                               \
    uint4 p;                                                                  \
    p.x = cpk(bv[j][0].x, bv[j][0].y); p.y = cpk(bv[j][0].z, bv[j][0].w);     \
    p.z = cpk(bv[j][1].x, bv[j][1].y); p.w = cpk(bv[j][1].z, bv[j][1].w);     \
    *(uint4*)(lds + BOFF + (bbuf) * BBUF + bdst[j]) = p;                      \
  }                                                                           \
} while (0)

#define COMPUTE(abuf, bbuf) do {                                              \
  const unsigned char* Abase = lds + (abuf) * ABUF + abase_off;               \
  const unsigned char* Bbase = lds + BOFF + (bbuf) * BBUF + bbase_off;        \
  short8 a0 = *(const short8*)(Abase);                                        \
  short8 a1 = *(const short8*)(Abase + 1024);                                 \
  short8 a2 = *(const short8*)(Abase + 2048);                                 \
  __builtin_amdgcn_s_setprio(1);                                              \
  _Pragma("unroll")                                                           \
  for (int n = 0; n < 12; n++) {                                              \
    short8 b = *(const short8*)(Bbase + n * 1024);                            \
    acc[0][n] = __builtin_amdgcn_mfma_f32_16x16x32_bf16(a0, b, acc[0][n], 0, 0, 0); \
    acc[1][n] = __builtin_amdgcn_mfma_f32_16x16x32_bf16(a1, b, acc[1][n], 0, 0, 0); \
    acc[2][n] = __builtin_amdgcn_mfma_f32_16x16x32_bf16(a2, b, acc[2][n], 0, 0, 0); \
  }                                                                           \
  __builtin_amdgcn_s_setprio(0);                                              \
} while (0)

#define GEMM_STEP_F(kt, CB, PB) do {                                          \
    if ((kt) + 1 < NK) LOAD_B((kt) + 1);                                      \
    if ((kt) + 2 < NK) STAGE_A(PB, (kt) + 2);                                 \
    COMPUTE(CB, (kt) & 1);                                                    \
    if ((kt) + 1 < NK) PACK_B(((kt) + 1) & 1);                                \
    ENDSTEP();                                                                \
  } while (0)

#define GEMM_PIPE_F() do {                                                    \
  STAGE_A(0, 0); STAGE_A(1, 1); LOAD_B(0);                                    \
  PACK_B(0);                                                                  \
  ENDSTEP();                                                                  \
  int ca = 0;                                                                 \
  _Pragma("unroll 1")                                                         \
  for (int u = 0; u < NK / 2; u++) {                                          \
    int kt = 2 * u;                                                           \
    int ca1 = ca + 1; if (ca1 >= 3) ca1 -= 3;                                 \
    int ca2 = ca + 2; if (ca2 >= 3) ca2 -= 3;                                 \
    if (kt + 2 < NK) STAGE_A(ca2, kt + 2);                                    \
    if (kt + 1 < NK) LOAD_B(kt + 1);                                          \
    COMPUTE(ca, 0);                                                           \
    if (kt + 1 < NK) PACK_B(1);                                               \
    ENDSTEP();                                                                \
    if (kt + 3 < NK) STAGE_A(ca, kt + 3);                                     \
    if (kt + 2 < NK) LOAD_B(kt + 2);                                          \
    COMPUTE(ca1, 1);                                                          \
    if (kt + 2 < NK) PACK_B(0);                                               \
    ENDSTEP();                                                                \
    ca = ca2;                                                                 \
  }                                                                           \
} while (0)

// ---- fallback gemm1 (== R5) ----
__global__ __launch_bounds__(256, 2) void k_gemm1_f(
    const unsigned short* __restrict__ t_bf16,
    const float* __restrict__ w1, const float* __restrict__ b1,
    const int* __restrict__ perm_tok, const int* __restrict__ d_off,
    unsigned short* __restrict__ act)
{
  __shared__ __align__(16) unsigned char lds[3 * ABUF + 2 * BBUF];
  const int total = d_off[16];
  int bid = blockIdx.x;
  int wg = (bid & 7) * (G1 / 8) + (bid >> 3);
  int ct = wg / MAX_RT, rt = wg % MAX_RT;
  int rowbase = rt * PADM;
  if (rowbase >= total) return;
  int e = 0;
#pragma unroll
  for (int q = 0; q < E_NUM; q++) if (d_off[q + 1] <= rowbase) e = q + 1;

  int tid = threadIdx.x, lane = tid & 63, wv = tid >> 6;
  int lr = lane & 15, ch = lane >> 4;
  unsigned swz16 = (unsigned)((ch ^ ((lr >> 1) & 3)) << 4);
  unsigned abase_off = (unsigned)(wv * 3072 + lr * 64) + swz16;
  unsigned bbase_off = (unsigned)(lr * 64) + swz16;

  const unsigned short* aptr[3]; unsigned adst[3];
#pragma unroll
  for (int i = 0; i < 3; i++) {
    int cl = tid + 256 * i;
    int r = cl >> 2, c = cl & 3;
    int tok = perm_tok[rowbase + r];
    aptr[i] = t_bf16 + (size_t)tok * H_DIM + ((c ^ ((r >> 1) & 3)) * 8);
    adst[i] = (unsigned)cl * 16;
  }
  const float4* bptr[3]; unsigned bdst[3];
#pragma unroll
  for (int j = 0; j < 3; j++) {
    int idx = tid + 256 * j;
    int rr = idx >> 2, c = idx & 3;
    size_t grow = (size_t)e * (2 * H_DIM) +
                  (rr < 96 ? (size_t)(ct * 96 + rr) : (size_t)(H_DIM + ct * 96 + (rr - 96)));
    bptr[j] = (const float4*)(w1 + grow * H_DIM) + c * 2;
    bdst[j] = (unsigned)(rr * 64 + ((c ^ ((rr >> 1) & 3)) << 4));
  }

  f32x4 zero = {0.f, 0.f, 0.f, 0.f};
  f32x4 acc[3][12];
#pragma unroll
  for (int m = 0; m < 3; m++)
#pragma unroll
    for (int n = 0; n < 12; n++) acc[m][n] = zero;
  float4 bv[3][2];

  GEMM_PIPE_F();

  int rq = lane >> 4;
#pragma unroll
  for (int m = 0; m < 3; m++) {
    int row0 = rowbase + wv * 48 + m * 16 + rq * 4;
#pragma unroll
    for (int n = 0; n < 6; n++) {
      int col = ct * 96 + n * 16 + lr;
      float bg = b1[(size_t)e * (2 * H_DIM) + col];
      float bl = b1[(size_t)e * (2 * H_DIM) + H_DIM + col];
#pragma unroll
      for (int j = 0; j < 4; j++) {
        float g = acc[m][n][j] + bg;
        float l = acc[m][n + 6][j] + bl;
        float s = 1.f / (1.f + __expf(-ALPHA * g));
        act[(size_t)(row0 + j) * H_DIM + col] = f2bf(g * s * (l + 1.f));
      }
    }
  }
}

// ---- fallback gemm2 (== R5) ----
__global__ __launch_bounds__(256, 2) void k_gemm2_f(
    const unsigned short* __restrict__ act,
    const float* __restrict__ w2, const float* __restrict__ b2,
    const int* __restrict__ perm_tok, const float* __restrict__ perm_w,
    const int* __restrict__ d_off,
    float* __restrict__ out)
{
  __shared__ __align__(16) unsigned char lds[3 * ABUF + 2 * BBUF];
  __shared__ int stok[PADM]; __shared__ float swt[PADM];
  const int total = d_off[16];
  int bid = blockIdx.x;
  int wg = (bid & 7) * (G2 / 8) + (bid >> 3);
  int ct = wg / MAX_RT, rt = wg % MAX_RT;
  int rowbase = rt * PADM;
  if (rowbase >= total) return;
  int e = 0;
#pragma unroll
  for (int q = 0; q < E_NUM; q++) if (d_off[q + 1] <= rowbase) e = q + 1;

  int tid = threadIdx.x, lane = tid & 63, wv = tid >> 6;
  int lr = lane & 15, ch = lane >> 4;
  unsigned swz16 = (unsigned)((ch ^ ((lr >> 1) & 3)) << 4);
  unsigned abase_off = (unsigned)(wv * 3072 + lr * 64) + swz16;
  unsigned bbase_off = (unsigned)(lr * 64) + swz16;

  if (tid < PADM) { stok[tid] = perm_tok[rowbase + tid]; swt[tid] = perm_w[rowbase + tid]; }

  const unsigned short* aptr[3]; unsigned adst[3];
#pragma unroll
  for (int i = 0; i < 3; i++) {
    int cl = tid + 256 * i;
    int r = cl >> 2, c = cl & 3;
    aptr[i] = act + (size_t)(rowbase + r) * H_DIM + ((c ^ ((r >> 1) & 3)) * 8);
    adst[i] = (unsigned)cl * 16;
  }
  const float4* bptr[3]; unsigned bdst[3];
#pragma unroll
  for (int j = 0; j < 3; j++) {
    int idx = tid + 256 * j;
    int rr = idx >> 2, c = idx & 3;
    size_t grow = (size_t)e * H_DIM + (size_t)(ct * 192 + rr);
    bptr[j] = (const float4*)(w2 + grow * H_DIM) + c * 2;
    bdst[j] = (unsigned)(rr * 64 + ((c ^ ((rr >> 1) & 3)) << 4));
  }

  f32x4 zero = {0.f, 0.f, 0.f, 0.f};
  f32x4 acc[3][12];
#pragma unroll
  for (int m = 0; m < 3; m++)
#pragma unroll
    for (int n = 0; n < 12; n++) acc[m][n] = zero;
  float4 bv[3][2];

  GEMM_PIPE_F();

  int rq = lane >> 4;
#pragma unroll
  for (int m = 0; m < 3; m++) {
    int rl0 = wv * 48 + m * 16 + rq * 4;
#pragma unroll
    for (int n = 0; n < 12; n++) {
      int col = ct * 192 + n * 16 + lr;
      float b2v = b2[(size_t)e * H_DIM + col];
#pragma unroll
      for (int j = 0; j < 4; j++) {
        int rl = rl0 + j;
        float w = swt[rl];
        if (w != 0.f)
          atomicAdd(out + (size_t)stok[rl] * H_DIM + col, (acc[m][n][j] + b2v) * w);
      }
    }
  }
}

// ================== BF16-weight GEMM (all-gload_lds, counted vmcnt) ==================
// 2x2 waves: wr=wv&1 rows 96, wc=wv>>1 cols. 3 buffers, depth-2, 1 barrier/step.
#define STAGE_BW(bbuf, ktn) do {                                              \
  _Pragma("unroll")                                                           \
  for (int i = 0; i < 3; i++)                                                 \
    gl_lds16(bpt[i] + (size_t)(ktn) * BK, lds + BOFF + (bbuf) * BBUF + adst[i]); \
} while (0)

#define WWAIT(full) do {                                                      \
    if (full) asm volatile("s_waitcnt vmcnt(6)" ::: "memory");                \
    else      asm volatile("s_waitcnt vmcnt(0)" ::: "memory");                \
    __builtin_amdgcn_sched_barrier(0);                                        \
    __builtin_amdgcn_s_barrier();                                             \
    __builtin_amdgcn_sched_barrier(0);                                        \
  } while (0)

#define WSTEP(kt, CB, SB, COMP) do {                                          \
    if ((kt) + 2 < NK) { STAGE_A(SB, (kt) + 2); STAGE_BW(SB, (kt) + 2); }     \
    COMP(CB);                                                                 \
    if ((kt) + 1 < NK) WWAIT((kt) + 2 < NK);                                  \
  } while (0)

#define WPIPE(COMP) do {                                                      \
  STAGE_A(0, 0); STAGE_BW(0, 0);                                              \
  STAGE_A(1, 1); STAGE_BW(1, 1);                                              \
  WWAIT(1);                                                                   \
  _Pragma("unroll 1")                                                         \
  for (int u = 0; u < NK / 3; u++) {                                          \
    int kt = 3 * u;                                                           \
    WSTEP(kt,     0, 2, COMP);                                                \
    WSTEP(kt + 1, 1, 0, COMP);                                                \
    WSTEP(kt + 2, 2, 1, COMP);                                                \
  }                                                                           \
} while (0)

#define COMP_G1(cb) do {                                                      \
  const unsigned char* Ab = lds + (cb) * ABUF;                                \
  const unsigned char* Bb = lds + BOFF + (cb) * BBUF;                         \
  short8 a_[6];                                                               \
  _Pragma("unroll")                                                           \
  for (int mf = 0; mf < 6; mf++) a_[mf] = *(const short8*)(Ab + abase + mf * 1024); \
  __builtin_amdgcn_s_setprio(1);                                              \
  _Pragma("unroll")                                                           \
  for (int nf = 0; nf < 3; nf++) {                                            \
    short8 bg = *(const short8*)(Bb + bgbase + nf * 1024);                    \
    short8 bl = *(const short8*)(Bb + blbase + nf * 1024);                    \
    _Pragma("unroll")                                                         \
    for (int mf = 0; mf < 6; mf++) {                                          \
      accg[mf][nf] = __builtin_amdgcn_mfma_f32_16x16x32_bf16(a_[mf], bg, accg[mf][nf], 0, 0, 0); \
      accl[mf][nf] = __builtin_amdgcn_mfma_f32_16x16x32_bf16(a_[mf], bl, accl[mf][nf], 0, 0, 0); \
    }                                                                         \
  }                                                                           \
  __builtin_amdgcn_s_setprio(0);                                              \
} while (0)

#define COMP_G2(cb) do {                                                      \
  const unsigned char* Ab = lds + (cb) * ABUF;                                \
  const unsigned char* Bb = lds + BOFF + (cb) * BBUF;                         \
  short8 a_[6];                                                               \
  _Pragma("unroll")                                                           \
  for (int mf = 0; mf < 6; mf++) a_[mf] = *(const short8*)(Ab + abase + mf * 1024); \
  __builtin_amdgcn_s_setprio(1);                                              \
  _Pragma("unroll")                                                           \
  for (int nf = 0; nf < 6; nf++) {                                            \
    short8 b = *(const short8*)(Bb + bbase + nf * 1024);                      \
    _Pragma("unroll")                                                         \
    for (int mf = 0; mf < 6; mf++)                                            \
      acc[mf][nf] = __builtin_amdgcn_mfma_f32_16x16x32_bf16(a_[mf], b, acc[mf][nf], 0, 0, 0); \
  }                                                                           \
  __builtin_amdgcn_s_setprio(0);                                              \
} while (0)

__global__ __launch_bounds__(256, 2) void k_gemm1_w(
    const unsigned short* __restrict__ t_bf16,
    const unsigned short* __restrict__ w1b, const float* __restrict__ b1,
    const int* __restrict__ perm_tok, const int* __restrict__ d_off,
    unsigned short* __restrict__ act)
{
  __shared__ __align__(16) unsigned char lds[3 * ABUF + 3 * BBUF];  // 72 KB
  const int total = d_off[16];
  int bid = blockIdx.x;
  int wg = (bid & 7) * (G1 / 8) + (bid >> 3);
  int ct = wg / MAX_RT, rt = wg % MAX_RT;
  int rowbase = rt * PADM;
  if (rowbase >= total) return;
  int e = 0;
#pragma unroll
  for (int q = 0; q < E_NUM; q++) if (d_off[q + 1] <= rowbase) e = q + 1;

  int tid = threadIdx.x, lane = tid & 63, wv = tid >> 6;
  int wr = wv & 1, wc = wv >> 1;
  int lr = lane & 15, ch = lane >> 4;
  unsigned swz16 = (unsigned)((ch ^ ((lr >> 1) & 3)) << 4);
  unsigned abase  = (unsigned)((wr * 96 + lr) * 64) + swz16;        // +mf*1024
  unsigned bgbase = (unsigned)((wc * 48 + lr) * 64) + swz16;        // +nf*1024
  unsigned blbase = bgbase + 96 * 64;

  const unsigned short* aptr[3]; const unsigned short* bpt[3]; unsigned adst[3];
#pragma unroll
  for (int i = 0; i < 3; i++) {
    int cl = tid + 256 * i;
    int r = cl >> 2, c = cl & 3;
    int cs = (c ^ ((r >> 1) & 3)) * 8;
    int tok = perm_tok[rowbase + r];
    aptr[i] = t_bf16 + (size_t)tok * H_DIM + cs;
    size_t grow = (size_t)e * (2 * H_DIM) +
                  (r < 96 ? (size_t)(ct * 96 + r) : (size_t)(H_DIM + ct * 96 + (r - 96)));
    bpt[i] = w1b + grow * H_DIM + cs;
    adst[i] = (unsigned)cl * 16;
  }

  f32x4 zero = {0.f, 0.f, 0.f, 0.f};
  f32x4 accg[6][3], accl[6][3];
#pragma unroll
  for (int m = 0; m < 6; m++)
#pragma unroll
    for (int n = 0; n < 3; n++) { accg[m][n] = zero; accl[m][n] = zero; }

  WPIPE(COMP_G1);

  int rq = lane >> 4;
#pragma unroll
  for (int mf = 0; mf < 6; mf++) {
    int row0 = rowbase + wr * 96 + mf * 16 + rq * 4;
#pragma unroll
    for (int nf = 0; nf < 3; nf++) {
      int col = ct * 96 + wc * 48 + nf * 16 + lr;
      float bg = b1[(size_t)e * (2 * H_DIM) + col];
      float bl = b1[(size_t)e * (2 * H_DIM) + H_DIM + col];
#pragma unroll
      for (int j = 0; j < 4; j++) {
        float g = accg[mf][nf][j] + bg;
        float l = accl[mf][nf][j] + bl;
        float s = 1.f / (1.f + __expf(-ALPHA * g));
        act[(size_t)(row0 + j) * H_DIM + col] = f2bf(g * s * (l + 1.f));
      }
    }
  }
}

__global__ __launch_bounds__(256, 2) void k_gemm2_w(
    const unsigned short* __restrict__ act,
    const unsigned short* __restrict__ w2b, const float* __restrict__ b2,
    const int* __restrict__ perm_tok, const float* __restrict__ perm_w,
    const int* __restrict__ d_off,
    float* __restrict__ out)
{
  __shared__ __align__(16) unsigned char lds[3 * ABUF + 3 * BBUF];  // 72 KB
  __shared__ int stok[PADM]; __shared__ float swt[PADM];
  const int total = d_off[16];
  int bid = blockIdx.x;
  int wg = (bid & 7) * (G2 / 8) + (bid >> 3);
  int ct = wg / MAX_RT, rt = wg % MAX_RT;
  int rowbase = rt * PADM;
  if (rowbase >= total) return;
  int e = 0;
#pragma unroll
  for (int q = 0; q < E_NUM; q++) if (d_off[q + 1] <= rowbase) e = q + 1;

  int tid = threadIdx.x, lane = tid & 63, wv = tid >> 6;
  int wr = wv & 1, wc = wv >> 1;
  int lr = lane & 15, ch = lane >> 4;
  unsigned swz16 = (unsigned)((ch ^ ((lr >> 1) & 3)) << 4);
  unsigned abase = (unsigned)((wr * 96 + lr) * 64) + swz16;
  unsigned bbase = (unsigned)((wc * 96 + lr) * 64) + swz16;

  if (tid < PADM) { stok[tid] = perm_tok[rowbase + tid]; swt[tid] = perm_w[rowbase + tid]; }

  const unsigned short* aptr[3]; const unsigned short* bpt[3]; unsigned adst[3];
#pragma unroll
  for (int i = 0; i < 3; i++) {
    int cl = tid + 256 * i;
    int r = cl >> 2, c = cl & 3;
    int cs = (c ^ ((r >> 1) & 3)) * 8;
    aptr[i] = act + (size_t)(rowbase + r) * H_DIM + cs;
    bpt[i] = w2b + ((size_t)e * H_DIM + (size_t)(ct * 192 + r)) * H_DIM + cs;
    adst[i] = (unsigned)cl * 16;
  }

  f32x4 zero = {0.f, 0.f, 0.f, 0.f};
  f32x4 acc[6][6];
#pragma unroll
  for (int m = 0; m < 6; m++)
#pragma unroll
    for (int n = 0; n < 6; n++) acc[m][n] = zero;

  WPIPE(COMP_G2);

  int rq = lane >> 4;
#pragma unroll
  for (int mf = 0; mf < 6; mf++) {
    int rl0 = wr * 96 + mf * 16 + rq * 4;
#pragma unroll
    for (int nf = 0; nf < 6; nf++) {
      int col = ct * 192 + wc * 96 + nf * 16 + lr;
      float b2v = b2[(size_t)e * H_DIM + col];
#pragma unroll
      for (int j = 0; j < 4; j++) {
        int rl = rl0 + j;
        float w = swt[rl];
        if (w != 0.f)
          atomicAdd(out + (size_t)stok[rl] * H_DIM + col, (acc[mf][nf][j] + b2v) * w);
      }
    }
  }
}

// ---------------- launch ----------------
extern "C" void kernel_launch(void* const* d_in, const int* in_sizes, int n_in,
                              void* d_out, int out_size, void* d_ws, size_t ws_size,
                              hipStream_t stream)
{
  const float* x      = (const float*)d_in[0];
  const float* norm_w = (const float*)d_in[1];
  const float* gate_w = (const float*)d_in[2];
  const float* gate_b = (const float*)d_in[3];
  const float* w1     = (const float*)d_in[4];
  const float* b1     = (const float*)d_in[5];
  const float* w2     = (const float*)d_in[6];
  const float* b2     = (const float*)d_in[7];
  float* out = (float*)d_out;
  char* ws = (char*)d_ws;

  // shared ws layout
  unsigned short* t_bf16  = (unsigned short*)(ws);                    // 23,592,960
  unsigned short* act     = (unsigned short*)(ws + 23592960);         // 115,015,680
  int*            topk_id = (int*)(ws + 138608640);
  float*          topk_w  = (float*)(ws + 138674176);
  int*            perm_tk = (int*)(ws + 138739712);
  float*          perm_w  = (float*)(ws + 138819584);
  int*            counts  = (int*)(ws + 138899456);
  int*            d_off   = (int*)(ws + 138899520);
  // big-ws extension: bf16 weights (w2 overlays w1 after gemm1)
  unsigned short* wb      = (unsigned short*)(ws + 138900480);        // 132,710,400
  const size_t NEED = 138900480ULL + 132710400ULL;                    // ~271.6 MB
  bool bigws = ws_size >= NEED;

  hipMemsetAsync(counts, 0, 64, stream);
  hipLaunchKernelGGL(k_norm_gate, dim3(T_TOK), dim3(256), 0, stream,
                     x, norm_w, gate_w, gate_b, out, t_bf16, topk_id, topk_w, counts);
  hipLaunchKernelGGL(k_offsets, dim3(1), dim3(64), 0, stream, counts, d_off);
  hipLaunchKernelGGL(k_fill, dim3(16), dim3(256), 0, stream,
                     topk_id, topk_w, counts, d_off, perm_tk, perm_w);
  if (bigws) {
    hipLaunchKernelGGL(k_cvt, dim3(2048), dim3(256), 0, stream, w1, wb, 33177600);
    hipLaunchKernelGGL(k_gemm1_w, dim3(G1), dim3(256), 0, stream,
                       t_bf16, wb, b1, perm_tk, d_off, act);
    hipLaunchKernelGGL(k_cvt, dim3(2048), dim3(256), 0, stream, w2, wb, 16588800);
    hipLaunchKernelGGL(k_gemm2_w, dim3(G2), dim3(256), 0, stream,
                       act, wb, b2, perm_tk, perm_w, d_off, out);
  } else {
    hipLaunchKernelGGL(k_gemm1_f, dim3(G1), dim3(256), 0, stream,
                       t_bf16, w1, b1, perm_tk, d_off, act);
    hipLaunchKernelGGL(k_gemm2_f, dim3(G2), dim3(256), 0, stream,
                       act, w2, b2, perm_tk, perm_w, d_off, out);
  }
}

// Round 8
// 1489.474 us; speedup vs baseline: 3.9916x; 1.9191x over previous
//
#include <hip/hip_runtime.h>
#include <hip/hip_bf16.h>
#include <math.h>
#include <stdint.h>

// Problem constants
#define T_TOK 4096
#define H_DIM 2880
#define E_NUM 16
#define ALPHA 1.702f
#define EPS_RMS 1e-5f

// GEMM tiling (R5-proven): BM=192 (4 waves x 3 m-frags), BN=192 eff, BK=32.
// A: 3-buffer LDS depth-2 via global_load_lds (register-free).
// B: 2-buffer LDS, depth-1 register prefetch (24 VGPR). No vmcnt(0) in loop.
#define PADM 192
#define BK 32
#define NK (H_DIM / BK)       // 90
#define MAX_RT 104
#define NCT1 30
#define NCT2 15
#define G1 (MAX_RT * NCT1)    // 3120 (div 8)
#define G2 (MAX_RT * NCT2)    // 1560 (div 8)
#define ABUF 12288
#define BBUF 12288
#define BOFF 36864            // 3*ABUF; total LDS 60 KB

typedef __attribute__((ext_vector_type(8))) short short8;
typedef __attribute__((ext_vector_type(4))) float f32x4;

__device__ __forceinline__ unsigned short f2bf(float f) {
  unsigned u = __float_as_uint(f);
  return (unsigned short)((u + 0x7fffu + ((u >> 16) & 1u)) >> 16);
}
__device__ __forceinline__ unsigned cpk(float a, float b) {
  unsigned r;
  asm("v_cvt_pk_bf16_f32 %0, %1, %2" : "=v"(r) : "v"(a), "v"(b));
  return r;
}
__device__ __forceinline__ float bf2f(unsigned short s) {
  return __uint_as_float((unsigned)s << 16);
}
__device__ __forceinline__ void gl_lds16(const void* g, unsigned char* lds_dst) {
  __builtin_amdgcn_global_load_lds(
      (const __attribute__((address_space(1))) void*)g,
      (__attribute__((address_space(3))) void*)lds_dst, 16, 0, 0);
}
#define ENDSTEP() do {                                           \
    asm volatile("s_waitcnt lgkmcnt(0)" ::: "memory");           \
    __builtin_amdgcn_s_barrier();                                \
    __builtin_amdgcn_sched_barrier(0);                           \
  } while (0)

// ---------------- K1: rmsnorm + fp32 gate + top4 (no residual write) ----------------
__global__ __launch_bounds__(256) void k_norm_gate(
    const float* __restrict__ x, const float* __restrict__ norm_w,
    const float* __restrict__ gate_w, const float* __restrict__ gate_b,
    unsigned short* __restrict__ t_out,
    int* __restrict__ topk_id, float* __restrict__ topk_w,
    int* __restrict__ counts)
{
  int t = blockIdx.x, tid = threadIdx.x;
  const float4* xr = (const float4*)(x + (size_t)t * H_DIM);
  float4 xa[3];
  float ss = 0.f;
  int j = 0;
  for (int i = tid; i < 720; i += 256, j++) {
    float4 v = xr[i]; xa[j] = v;
    ss += v.x * v.x + v.y * v.y + v.z * v.z + v.w * v.w;
  }
#pragma unroll
  for (int o = 1; o < 64; o <<= 1) ss += __shfl_xor(ss, o, 64);
  __shared__ float red[4];
  if ((tid & 63) == 0) red[tid >> 6] = ss;
  __syncthreads();
  float rs = rsqrtf((red[0] + red[1] + red[2] + red[3]) * (1.f / H_DIM) + EPS_RMS);

  float part[16];
#pragma unroll
  for (int q = 0; q < 16; q++) part[q] = 0.f;
  j = 0;
  for (int i = tid; i < 720; i += 256, j++) {
    float4 v = xa[j];
    float4 w = ((const float4*)norm_w)[i];
    float t0 = v.x * rs * w.x, t1 = v.y * rs * w.y;
    float t2 = v.z * rs * w.z, t3 = v.w * rs * w.w;
    ushort4 b; b.x = f2bf(t0); b.y = f2bf(t1); b.z = f2bf(t2); b.w = f2bf(t3);
    ((ushort4*)(t_out + (size_t)t * H_DIM))[i] = b;
#pragma unroll
    for (int q = 0; q < 16; q++) {    // fp32 logits (selection accuracy)
      float4 g = ((const float4*)(gate_w + (size_t)q * H_DIM))[i];
      part[q] += t0 * g.x + t1 * g.y + t2 * g.z + t3 * g.w;
    }
  }
  __shared__ float lg[4][16];
#pragma unroll
  for (int q = 0; q < 16; q++) {
    float p = part[q];
#pragma unroll
    for (int o = 1; o < 64; o <<= 1) p += __shfl_xor(p, o, 64);
    if ((tid & 63) == 0) lg[tid >> 6][q] = p;
  }
  __syncthreads();
  if (tid == 0) {
    float logit[16];
    for (int q = 0; q < 16; q++)
      logit[q] = lg[0][q] + lg[1][q] + lg[2][q] + lg[3][q] + gate_b[q];
    unsigned used = 0; int idx[4]; float val[4];
    for (int k = 0; k < 4; k++) {           // ties -> lowest index
      float best = -3.4e38f; int bi = 0;
      for (int q = 0; q < 16; q++)
        if (!((used >> q) & 1u) && logit[q] > best) { best = logit[q]; bi = q; }
      used |= 1u << bi; idx[k] = bi; val[k] = best;
    }
    float s0 = 0.f, w4[4];
    for (int k = 0; k < 4; k++) { w4[k] = expf(val[k] - val[0]); s0 += w4[k]; }
    for (int k = 0; k < 4; k++) {
      topk_id[t * 4 + k] = idx[k];
      topk_w[t * 4 + k] = w4[k] / s0;
      atomicAdd(&counts[idx[k]], 1);
    }
  }
}

// ---------------- K2a: padded prefix offsets ----------------
__global__ void k_offsets(const int* __restrict__ counts, int* __restrict__ d_off) {
  if (threadIdx.x == 0) {
    int acc = 0;
    for (int q = 0; q < 16; q++) {
      d_off[q] = acc;
      acc += ((counts[q] + PADM - 1) / PADM) * PADM;
    }
    d_off[16] = acc;
  }
}

// ---------------- K2b: routing lists (token order); padding tok = -1 ----------------
__global__ __launch_bounds__(256) void k_fill(
    const int* __restrict__ topk_id, const float* __restrict__ topk_w,
    const int* __restrict__ counts, const int* __restrict__ d_off,
    int* __restrict__ perm_tok, float* __restrict__ perm_w,
    int* __restrict__ perm_sl)
{
  int e = blockIdx.x;
  int base = d_off[e], pe = d_off[e + 1] - base, cnt = counts[e];
  int tid = threadIdx.x, lane = tid & 63, wv = tid >> 6;
  __shared__ int wsum[4];
  int pos = 0;
  for (int c0 = 0; c0 < T_TOK; c0 += 256) {
    int tok = c0 + tid;
    int4 ids = ((const int4*)topk_id)[tok];
    int flag = 0, slot = 0;
    if (ids.x == e) { flag = 1; slot = 0; }
    else if (ids.y == e) { flag = 1; slot = 1; }
    else if (ids.z == e) { flag = 1; slot = 2; }
    else if (ids.w == e) { flag = 1; slot = 3; }
    unsigned long long b = __ballot(flag);
    int wprefix = __popcll(b & ((1ULL << lane) - 1ULL));
    if (lane == 0) wsum[wv] = __popcll(b);
    __syncthreads();
    int woff = 0;
    for (int i = 0; i < wv; i++) woff += wsum[i];
    int tot = wsum[0] + wsum[1] + wsum[2] + wsum[3];
    if (flag) {
      int p = base + pos + woff + wprefix;
      perm_tok[p] = tok;
      perm_w[p] = topk_w[tok * 4 + slot];
      perm_sl[p] = slot;
    }
    pos += tot;
    __syncthreads();
  }
  for (int i = cnt + tid; i < pe; i += 256) {   // padding rows
    perm_tok[base + i] = -1;
    perm_w[base + i] = 0.f;
    perm_sl[base + i] = 0;
  }
}

// ---- shared GEMM macros (R5-proven) ----
#define STAGE_A(abuf, ktn) do {                                               \
  _Pragma("unroll")                                                           \
  for (int i = 0; i < 3; i++)                                                 \
    gl_lds16(aptr[i] + (size_t)(ktn) * BK, lds + (abuf) * ABUF + adst[i]);    \
} while (0)

#define LOAD_B(ktn) do {                                                      \
  _Pragma("unroll")                                                           \
  for (int j = 0; j < 3; j++) {                                               \
    bv[j][0] = bptr[j][(ktn) * 8];                                            \
    bv[j][1] = bptr[j][(ktn) * 8 + 1];                                        \
  }                                                                           \
} while (0)

#define PACK_B(bbuf) do {                                                     \
  _Pragma("unroll")                                                           \
  for (int j = 0; j < 3; j++) {                                               \
    uint4 p;                                                                  \
    p.x = cpk(bv[j][0].x, bv[j][0].y); p.y = cpk(bv[j][0].z, bv[j][0].w);     \
    p.z = cpk(bv[j][1].x, bv[j][1].y); p.w = cpk(bv[j][1].z, bv[j][1].w);     \
    *(uint4*)(lds + BOFF + (bbuf) * BBUF + bdst[j]) = p;                      \
  }                                                                           \
} while (0)

#define COMPUTE(abuf, bbuf) do {                                              \
  const unsigned char* Abase = lds + (abuf) * ABUF + abase_off;               \
  const unsigned char* Bbase = lds + BOFF + (bbuf) * BBUF + bbase_off;        \
  short8 a0 = *(const short8*)(Abase);                                        \
  short8 a1 = *(const short8*)(Abase + 1024);                                 \
  short8 a2 = *(const short8*)(Abase + 2048);                                 \
  __builtin_amdgcn_s_setprio(1);                                              \
  _Pragma("unroll")                                                           \
  for (int n = 0; n < 12; n++) {                                              \
    short8 b = *(const short8*)(Bbase + n * 1024);                            \
    acc[0][n] = __builtin_amdgcn_mfma_f32_16x16x32_bf16(a0, b, acc[0][n], 0, 0, 0); \
    acc[1][n] = __builtin_amdgcn_mfma_f32_16x16x32_bf16(a1, b, acc[1][n], 0, 0, 0); \
    acc[2][n] = __builtin_amdgcn_mfma_f32_16x16x32_bf16(a2, b, acc[2][n], 0, 0, 0); \
  }                                                                           \
  __builtin_amdgcn_s_setprio(0);                                              \
} while (0)

#define GEMM_PIPE() do {                                                      \
  STAGE_A(0, 0); STAGE_A(1, 1); LOAD_B(0);                                    \
  PACK_B(0);                                                                  \
  ENDSTEP();                                                                  \
  int ca = 0;                                                                 \
  _Pragma("unroll 1")                                                         \
  for (int u = 0; u < NK / 2; u++) {                                          \
    int kt = 2 * u;                                                           \
    int ca1 = ca + 1; if (ca1 >= 3) ca1 -= 3;                                 \
    int ca2 = ca + 2; if (ca2 >= 3) ca2 -= 3;                                 \
    if (kt + 1 < NK) LOAD_B(kt + 1);                                          \
    if (kt + 2 < NK) STAGE_A(ca2, kt + 2);                                    \
    COMPUTE(ca, 0);                                                           \
    if (kt + 1 < NK) PACK_B(1);                                               \
    ENDSTEP();                                                                \
    if (kt + 2 < NK) LOAD_B(kt + 2);                                          \
    if (kt + 3 < NK) STAGE_A(ca, kt + 3);                                     \
    COMPUTE(ca1, 1);                                                          \
    if (kt + 2 < NK) PACK_B(0);                                               \
    ENDSTEP();                                                                \
    ca = ca2;                                                                 \
  }                                                                           \
} while (0)

// ================= K3: grouped gemm1 + bias + SwiGLU -> act (R5) =================
__global__ __launch_bounds__(256, 2) void k_gemm1(
    const unsigned short* __restrict__ t_bf16,
    const float* __restrict__ w1, const float* __restrict__ b1,
    const int* __restrict__ perm_tok, const int* __restrict__ d_off,
    unsigned short* __restrict__ act)
{
  __shared__ __align__(16) unsigned char lds[3 * ABUF + 2 * BBUF];  // 60 KB
  const int total = d_off[16];
  int bid = blockIdx.x;
  int wg = (bid & 7) * (G1 / 8) + (bid >> 3);   // XCD-chunked, rt fastest
  int ct = wg / MAX_RT, rt = wg % MAX_RT;
  int rowbase = rt * PADM;
  if (rowbase >= total) return;
  int e = 0;
#pragma unroll
  for (int q = 0; q < E_NUM; q++) if (d_off[q + 1] <= rowbase) e = q + 1;

  int tid = threadIdx.x, lane = tid & 63, wv = tid >> 6;
  int lr = lane & 15, ch = lane >> 4;
  unsigned swz16 = (unsigned)((ch ^ ((lr >> 1) & 3)) << 4);
  unsigned abase_off = (unsigned)(wv * 3072 + lr * 64) + swz16;
  unsigned bbase_off = (unsigned)(lr * 64) + swz16;

  const unsigned short* aptr[3]; unsigned adst[3];
#pragma unroll
  for (int i = 0; i < 3; i++) {
    int cl = tid + 256 * i;
    int r = cl >> 2, c = cl & 3;
    int tok = perm_tok[rowbase + r];
    if (tok < 0) tok = 0;                       // padding row: safe gather
    aptr[i] = t_bf16 + (size_t)tok * H_DIM + ((c ^ ((r >> 1) & 3)) * 8);
    adst[i] = (unsigned)cl * 16;
  }
  const float4* bptr[3]; unsigned bdst[3];
#pragma unroll
  for (int j = 0; j < 3; j++) {
    int idx = tid + 256 * j;
    int rr = idx >> 2, c = idx & 3;
    size_t grow = (size_t)e * (2 * H_DIM) +
                  (rr < 96 ? (size_t)(ct * 96 + rr) : (size_t)(H_DIM + ct * 96 + (rr - 96)));
    bptr[j] = (const float4*)(w1 + grow * H_DIM) + c * 2;
    bdst[j] = (unsigned)(rr * 64 + ((c ^ ((rr >> 1) & 3)) << 4));
  }

  f32x4 zero = {0.f, 0.f, 0.f, 0.f};
  f32x4 acc[3][12];
#pragma unroll
  for (int m = 0; m < 3; m++)
#pragma unroll
    for (int n = 0; n < 12; n++) acc[m][n] = zero;
  float4 bv[3][2];

  GEMM_PIPE();

  int rq = lane >> 4;
#pragma unroll
  for (int m = 0; m < 3; m++) {
    int row0 = rowbase + wv * 48 + m * 16 + rq * 4;
#pragma unroll
    for (int n = 0; n < 6; n++) {
      int col = ct * 96 + n * 16 + lr;
      float bg = b1[(size_t)e * (2 * H_DIM) + col];
      float bl = b1[(size_t)e * (2 * H_DIM) + H_DIM + col];
#pragma unroll
      for (int j = 0; j < 4; j++) {
        float g = acc[m][n][j] + bg;
        float l = acc[m][n + 6][j] + bl;
        float s = 1.f / (1.f + __expf(-ALPHA * g));
        act[(size_t)(row0 + j) * H_DIM + col] = f2bf(g * s * (l + 1.f));
      }
    }
  }
}

// ========== K4: grouped gemm2 + bias; weighted bf16 SLOT stores (no atomics) ==========
__global__ __launch_bounds__(256, 2) void k_gemm2(
    const unsigned short* __restrict__ act,
    const float* __restrict__ w2, const float* __restrict__ b2,
    const int* __restrict__ perm_tok, const float* __restrict__ perm_w,
    const int* __restrict__ perm_sl, const int* __restrict__ d_off,
    unsigned short* __restrict__ yslot)
{
  __shared__ __align__(16) unsigned char lds[3 * ABUF + 2 * BBUF];  // 60 KB
  __shared__ int stok[PADM]; __shared__ float swt[PADM]; __shared__ int ssl[PADM];
  const int total = d_off[16];
  int bid = blockIdx.x;
  int wg = (bid & 7) * (G2 / 8) + (bid >> 3);
  int ct = wg / MAX_RT, rt = wg % MAX_RT;
  int rowbase = rt * PADM;
  if (rowbase >= total) return;
  int e = 0;
#pragma unroll
  for (int q = 0; q < E_NUM; q++) if (d_off[q + 1] <= rowbase) e = q + 1;

  int tid = threadIdx.x, lane = tid & 63, wv = tid >> 6;
  int lr = lane & 15, ch = lane >> 4;
  unsigned swz16 = (unsigned)((ch ^ ((lr >> 1) & 3)) << 4);
  unsigned abase_off = (unsigned)(wv * 3072 + lr * 64) + swz16;
  unsigned bbase_off = (unsigned)(lr * 64) + swz16;

  if (tid < PADM) {
    stok[tid] = perm_tok[rowbase + tid];
    swt[tid] = perm_w[rowbase + tid];
    ssl[tid] = perm_sl[rowbase + tid];
  }

  const unsigned short* aptr[3]; unsigned adst[3];
#pragma unroll
  for (int i = 0; i < 3; i++) {
    int cl = tid + 256 * i;
    int r = cl >> 2, c = cl & 3;
    aptr[i] = act + (size_t)(rowbase + r) * H_DIM + ((c ^ ((r >> 1) & 3)) * 8);
    adst[i] = (unsigned)cl * 16;
  }
  const float4* bptr[3]; unsigned bdst[3];
#pragma unroll
  for (int j = 0; j < 3; j++) {
    int idx = tid + 256 * j;
    int rr = idx >> 2, c = idx & 3;
    size_t grow = (size_t)e * H_DIM + (size_t)(ct * 192 + rr);
    bptr[j] = (const float4*)(w2 + grow * H_DIM) + c * 2;
    bdst[j] = (unsigned)(rr * 64 + ((c ^ ((rr >> 1) & 3)) << 4));
  }

  f32x4 zero = {0.f, 0.f, 0.f, 0.f};
  f32x4 acc[3][12];
#pragma unroll
  for (int m = 0; m < 3; m++)
#pragma unroll
    for (int n = 0; n < 12; n++) acc[m][n] = zero;
  float4 bv[3][2];

  GEMM_PIPE();

  int rq = lane >> 4;
#pragma unroll
  for (int m = 0; m < 3; m++) {
    int rl0 = wv * 48 + m * 16 + rq * 4;
#pragma unroll
    for (int n = 0; n < 12; n++) {
      int col = ct * 192 + n * 16 + lr;
      float b2v = b2[(size_t)e * H_DIM + col];
#pragma unroll
      for (int j = 0; j < 4; j++) {
        int rl = rl0 + j;
        int tk = stok[rl];
        if (tk >= 0) {
          float y = (acc[m][n][j] + b2v) * swt[rl];
          yslot[((size_t)ssl[rl] * T_TOK + tk) * H_DIM + col] = f2bf(y);
        }
      }
    }
  }
}

// ---------------- K5: combine — out = x + sum_k slot_k ----------------
__global__ __launch_bounds__(256) void k_comb(
    const float* __restrict__ x, const unsigned short* __restrict__ yslot,
    float* __restrict__ out)
{
  const int n8 = T_TOK * H_DIM / 8;   // 1,474,560
  int i = blockIdx.x * 256 + threadIdx.x;
  int stride = gridDim.x * 256;
  for (; i < n8; i += stride) {
    float4 x0 = ((const float4*)x)[2 * i];
    float4 x1 = ((const float4*)x)[2 * i + 1];
    float s[8] = {x0.x, x0.y, x0.z, x0.w, x1.x, x1.y, x1.z, x1.w};
#pragma unroll
    for (int k = 0; k < 4; k++) {
      uint4 v = ((const uint4*)(yslot + (size_t)k * T_TOK * H_DIM))[i];
      unsigned u[4] = {v.x, v.y, v.z, v.w};
#pragma unroll
      for (int q = 0; q < 4; q++) {
        s[2 * q]     += __uint_as_float(u[q] << 16);
        s[2 * q + 1] += __uint_as_float(u[q] & 0xffff0000u);
      }
    }
    float4 o0 = {s[0], s[1], s[2], s[3]};
    float4 o1 = {s[4], s[5], s[6], s[7]};
    ((float4*)out)[2 * i] = o0;
    ((float4*)out)[2 * i + 1] = o1;
  }
}

// ---------------- launch ----------------
extern "C" void kernel_launch(void* const* d_in, const int* in_sizes, int n_in,
                              void* d_out, int out_size, void* d_ws, size_t ws_size,
                              hipStream_t stream)
{
  const float* x      = (const float*)d_in[0];
  const float* norm_w = (const float*)d_in[1];
  const float* gate_w = (const float*)d_in[2];
  const float* gate_b = (const float*)d_in[3];
  const float* w1     = (const float*)d_in[4];
  const float* b1     = (const float*)d_in[5];
  const float* w2     = (const float*)d_in[6];
  const float* b2     = (const float*)d_in[7];
  float* out = (float*)d_out;
  char* ws = (char*)d_ws;

  // ws layout (~233.4 MB; ws_size >= 271.6 MB verified in R7)
  unsigned short* t_bf16  = (unsigned short*)(ws);                    // 23,592,960
  unsigned short* act     = (unsigned short*)(ws + 23592960);         // 115,015,680
  int*            topk_id = (int*)(ws + 138608640);                   // 65,536
  float*          topk_w  = (float*)(ws + 138674176);                 // 65,536
  int*            perm_tk = (int*)(ws + 138739712);                   // 79,872
  float*          perm_w  = (float*)(ws + 138819584);                 // 79,872
  int*            perm_sl = (int*)(ws + 138899456);                   // 79,872
  int*            counts  = (int*)(ws + 138979328);                   // 64
  int*            d_off   = (int*)(ws + 138979392);                   // 68
  unsigned short* yslot   = (unsigned short*)(ws + 138979840);        // 94,371,840

  hipMemsetAsync(counts, 0, 64, stream);
  hipLaunchKernelGGL(k_norm_gate, dim3(T_TOK), dim3(256), 0, stream,
                     x, norm_w, gate_w, gate_b, t_bf16, topk_id, topk_w, counts);
  hipLaunchKernelGGL(k_offsets, dim3(1), dim3(64), 0, stream, counts, d_off);
  hipLaunchKernelGGL(k_fill, dim3(16), dim3(256), 0, stream,
                     topk_id, topk_w, counts, d_off, perm_tk, perm_w, perm_sl);
  hipLaunchKernelGGL(k_gemm1, dim3(G1), dim3(256), 0, stream,
                     t_bf16, w1, b1, perm_tk, d_off, act);
  hipLaunchKernelGGL(k_gemm2, dim3(G2), dim3(256), 0, stream,
                     act, w2, b2, perm_tk, perm_w, perm_sl, d_off, yslot);
  hipLaunchKernelGGL(k_comb, dim3(2048), dim3(256), 0, stream, x, yslot, out);
}